// Round 8
// baseline (55.767 us; speedup 1.0000x reference)
//
#include <hip/hip_runtime.h>
#include <cstdint>

#define BB 4
#define HH 2048
#define WW 2048
#define MAXT 21
#define BIGSQ 441
#define TW 128     // tile width (cols per block)
#define BH 128     // band height (output rows per block)
#define WROWS 170  // BH + 2*21 window rows needed per band

typedef float floatx4 __attribute__((ext_vector_type(4)));

static __device__ __forceinline__ uint32_t umin32(uint32_t a, uint32_t b) { return a < b ? a : b; }

struct HRow { uint2 uc, hl, hr; bool inimg; };

// Fused chamfer, column-band version. Block owns a 128x128 output tile and
// slides a 64-slot LDS window of h-distance^2 rows down the band:
//   prologue: h-pass rows lr=0..49 (gy = y0-21+lr) into window
//   per 8-row iter: load next rows early | relax+store 8 rows | h-pass 8 rows
// h-pass = R5-validated ballot/funnel/sentinel-ctz (pair scheme, 2px/lane);
// relax = R3-validated packed-u16 scheme (4 cols/lane).
__global__ __launch_bounds__(256) void fused(const int* __restrict__ in,
                                             float* __restrict__ out) {
    __shared__ uint16_t s[64][TW];      // 16 KiB rolling dh^2 window (packed u16)
    const int tid  = threadIdx.x;
    const int lane = tid & 63;
    const int w    = tid >> 6;
    const int li   = 63 - lane;
    const int hl2  = (lane & 31) << 1;
    const int x0   = blockIdx.x << 7;
    const int y0   = blockIdx.y << 7;
    const int b    = blockIdx.z;
    const long long base = (long long)b * HH * WW;
    const bool hasL = (x0 > 0);
    const bool hasR = (x0 + TW < WW);

    auto load_row = [&](int lr) -> HRow {
        HRow r;
        r.uc = make_uint2(0, 0); r.hl = make_uint2(0, 0); r.hr = make_uint2(0, 0);
        const int gy = y0 - 21 + lr;
        r.inimg = (gy >= 0) && (gy < HH);
        if (lr < WROWS && r.inimg) {
            const int* rp = in + base + (long long)gy * WW;
            r.uc = *(const uint2*)(rp + x0 + (lane << 1));
            if (hasL) r.hl = *(const uint2*)(rp + x0 - 64 + hl2);
            if (hasR) r.hr = *(const uint2*)(rp + x0 + TW + hl2);
        }
        return r;
    };

    auto compute_store = [&](int lr, const HRow& r) {
        uint32_t pk;
        if (r.inimg) {
            unsigned long long b0c = __ballot(r.uc.x != 0);
            unsigned long long b1c = __ballot(r.uc.y != 0);
            unsigned long long b0p = 0, b1p = 0, b0n = 0, b1n = 0;
            if (hasL) {   // left halo px x0-64..x0-1 = pairs 32..63 of prev chunk
                b0p = __ballot(lane < 32 && r.hl.x != 0) << 32;
                b1p = __ballot(lane < 32 && r.hl.y != 0) << 32;
            }
            if (hasR) {   // right halo px x0+128..x0+191 = pairs 0..31 of next chunk
                b0n = __ballot(lane < 32 && r.hr.x != 0);
                b1n = __ballot(lane < 32 && r.hr.y != 0);
            }
            // reversed-space masks with phase swap: RB_m = brev(B_{1-m})
            unsigned long long rb0c = __brevll(b1c), rb1c = __brevll(b0c);
            unsigned long long rb0p = __brevll(b1p), rb1p = __brevll(b0p);
            unsigned long long S0  = (b0c >> lane) | ((b0n << 1) << li);
            unsigned long long S1  = (b1c >> lane) | ((b1n << 1) << li);
            unsigned long long SL0 = (rb0c >> li)  | ((rb0p << 1) << lane);
            unsigned long long SL1 = (rb1c >> li)  | ((rb1p << 1) << lane);
            const uint32_t SEN = 1u << 11;  // t=11 -> d>=22 -> clamps to 21
            uint32_t s0 = (uint32_t)S0, s1 = (uint32_t)S1;
            uint32_t l0 = (uint32_t)SL0, l1 = (uint32_t)SL1;
            int t_s0  = __builtin_ctz(s0 | SEN);
            int t_s1  = __builtin_ctz(s1 | SEN);
            int t_s0s = __builtin_ctz((s0 >> 1) | SEN);
            int t_l0  = __builtin_ctz(l0 | SEN);
            int t_l1  = __builtin_ctz(l1 | SEN);
            int t_l0s = __builtin_ctz((l0 >> 1) | SEN);
            int d0 = min(min(2 * t_s0, 2 * t_s1 + 1), min(2 * t_l1, 2 * t_l0s + 1));
            int d1 = min(min(2 * t_s1, 2 * t_s0s + 1), min(2 * t_l0, 2 * t_l1 + 1));
            d0 = min(d0, MAXT);
            d1 = min(d1, MAXT);
            pk = (uint32_t)(d0 * d0) | ((uint32_t)(d1 * d1) << 16);
        } else {
            pk = BIGSQ | (BIGSQ << 16);     // outside image: never wins
        }
        *(uint32_t*)&s[lr & 63][lane << 1] = pk;
    };

    // ---- prologue: window rows lr = 0..49, waves striped, 2-stage pipeline ----
    {
        int lr = w;
        HRow cur = load_row(lr);
        while (lr < 50) {
            const int nxt = lr + 4;
            HRow nr = cur;
            if (nxt < 50) nr = load_row(nxt);
            compute_store(lr, cur);
            cur = nr;
            lr  = nxt;
        }
    }
    __syncthreads();

    const int ro = lane >> 5;            // row offset within wave's pair
    const int cg = (lane & 31) << 2;     // 4 adjacent cols per lane

    for (int i = 0; i < BH / 8; ++i) {
        const int yb = i << 3;
        // (a) issue next h-rows' loads early — latency hides under relax
        const int lr0 = yb + 50 + (w << 1);
        const int lr1 = lr0 + 1;
        HRow R0 = load_row(lr0);
        HRow R1 = load_row(lr1);

        // (b) relax + sqrt + store rows yb..yb+7 (wave w: rows yb+2w+ro)
        {
            const int j  = yb + (w << 1) + ro;   // output row in [0,128)
            const int lc = j + 21;               // window center
            uint2 q = *(const uint2*)&s[lc & 63][cg];
            uint32_t v0 = q.x & 0xffff, v1 = q.x >> 16;
            uint32_t v2 = q.y & 0xffff, v3 = q.y >> 16;
            for (int d = 1; d <= MAXT; ++d) {
                const uint32_t dd = (uint32_t)(d * d);
                uint32_t h  = v0 > v1 ? v0 : v1;
                uint32_t h2 = v2 > v3 ? v2 : v3;
                h = h > h2 ? h : h2;
                if (__all(dd >= h)) break;   // further candidates >= d^2 >= current
                uint2 a  = *(const uint2*)&s[(lc - d) & 63][cg];
                uint2 bq = *(const uint2*)&s[(lc + d) & 63][cg];
                const uint32_t dd2 = dd * 0x10001u;   // packed u16 add (<=882, no carry)
                uint32_t A0 = a.x + dd2, A1 = a.y + dd2;
                uint32_t B0 = bq.x + dd2, B1 = bq.y + dd2;
                v0 = umin32(v0, umin32(A0 & 0xffff, B0 & 0xffff));
                v1 = umin32(v1, umin32(A0 >> 16,    B0 >> 16));
                v2 = umin32(v2, umin32(A1 & 0xffff, B1 & 0xffff));
                v3 = umin32(v3, umin32(A1 >> 16,    B1 >> 16));
            }
            floatx4 o;
            o.x = sqrtf((float)v0);
            o.y = sqrtf((float)v1);
            o.z = sqrtf((float)v2);
            o.w = sqrtf((float)v3);
            floatx4* op = (floatx4*)&out[base + (long long)(y0 + j) * WW + x0 + cg];
            __builtin_nontemporal_store(o, op);
        }

        // (c) h-pass the 8 new window rows (slots disjoint from (b)'s reads)
        if (lr0 < WROWS) compute_store(lr0, R0);
        if (lr1 < WROWS) compute_store(lr1, R1);
        __syncthreads();
    }
}

extern "C" void kernel_launch(void* const* d_in, const int* in_sizes, int n_in,
                              void* d_out, int out_size, void* d_ws, size_t ws_size,
                              hipStream_t stream) {
    const int* unt = (const int*)d_in[0];
    float* out     = (float*)d_out;
    fused<<<dim3(WW / TW, HH / BH, BB), 256, 0, stream>>>(unt, out);
}

// Round 9
// 46.175 us; speedup vs baseline: 1.2077x; 1.2077x over previous
//
#include <hip/hip_runtime.h>
#include <cstdint>

#define BB 4
#define HH 2048
#define WW 2048
#define MAXT 21
#define BIGSQ 441
#define SEN (1u << 6)   // quad-dist sentinel: t=6 -> d>=21 -> clamps
#define TW 256          // tile width
#define BH 128          // output rows per block
#define WROWS 170       // BH + 2*21
#define RING 128        // LDS ring slots (span needed: 58 read + 16 write = 74)

typedef float floatx4 __attribute__((ext_vector_type(4)));

static __device__ __forceinline__ uint32_t umin32(uint32_t a, uint32_t b) { return a < b ? a : b; }
static __device__ __forceinline__ int imin(int a, int b) { return a < b ? a : b; }

struct HRow { uint4 core, hl, hr; bool inimg; };

// Fused chamfer v3. Block = 256x128 output tile, 8 waves, 128-slot rolling
// LDS ring of h-distance^2 rows (packed u16). H-pass = R7-validated quad
// ballot/funnel/sentinel-ctz scheme (4 px/lane, one uint4 load per row);
// halo chunks enter as 16-bit ballots at the correct mask positions
// (left: bits 48..63 of "prev" mask; right: bits 0..15 of "next").
// Relax = R3/R7-validated packed-u16 scheme, one full row per wave.
__global__ __launch_bounds__(512) void fused(const int* __restrict__ in,
                                             float* __restrict__ out) {
    __shared__ uint16_t s[RING][TW];    // 64 KiB
    const int tid  = threadIdx.x;
    const int lane = tid & 63;
    const int w    = tid >> 6;          // 0..7
    const int li   = 63 - lane;

    const int bid = blockIdx.x;                     // 512 blocks, %8==0
    const int swz = (bid & 7) * 64 + (bid >> 3);    // XCD-chunked, y-fastest
    const int b   = swz >> 7;
    const int rem = swz & 127;
    const int x0  = (rem >> 4) << 8;                // 8 x-tiles
    const int y0  = (rem & 15) << 7;                // 16 y-bands
    const long long base = (long long)b * HH * WW;
    const bool hasL = (x0 > 0);
    const bool hasR = (x0 + TW < WW);
    const bool lo16 = (lane < 16);

    auto load_row = [&](int lr) -> HRow {
        HRow r;
        r.core = make_uint4(0, 0, 0, 0);
        r.hl   = make_uint4(0, 0, 0, 0);
        r.hr   = make_uint4(0, 0, 0, 0);
        const int gy = y0 - 21 + lr;
        r.inimg = (gy >= 0) && (gy < HH);
        if (r.inimg) {
            const int* rp = in + base + (long long)gy * WW;
            r.core = *(const uint4*)(rp + x0 + (lane << 2));
            if (hasL && lo16) r.hl = *(const uint4*)(rp + x0 - 64 + (lane << 2));
            if (hasR && lo16) r.hr = *(const uint4*)(rp + x0 + TW + (lane << 2));
        }
        return r;
    };

    auto compute_store = [&](int lr, const HRow& r) {
        uint32_t pk0, pk1;
        if (r.inimg) {
            unsigned long long Bc[4], Bp[4], Bn[4], rbc[4], rbp[4];
            Bc[0] = __ballot(r.core.x != 0);
            Bc[1] = __ballot(r.core.y != 0);
            Bc[2] = __ballot(r.core.z != 0);
            Bc[3] = __ballot(r.core.w != 0);
            // left halo px x0-64..x0-1 = quads -16..-1 = bits 48..63 of prev mask
            Bp[0] = __ballot(lo16 && r.hl.x != 0) << 48;
            Bp[1] = __ballot(lo16 && r.hl.y != 0) << 48;
            Bp[2] = __ballot(lo16 && r.hl.z != 0) << 48;
            Bp[3] = __ballot(lo16 && r.hl.w != 0) << 48;
            // right halo px x0+256.. = quads 0..15 of next mask
            Bn[0] = __ballot(lo16 && r.hr.x != 0);
            Bn[1] = __ballot(lo16 && r.hr.y != 0);
            Bn[2] = __ballot(lo16 && r.hr.z != 0);
            Bn[3] = __ballot(lo16 && r.hr.w != 0);
            #pragma unroll
            for (int k = 0; k < 4; ++k) { rbc[k] = __brevll(Bc[k]); rbp[k] = __brevll(Bp[k]); }

            int a[4], bb[4], c[4], e[4];
            #pragma unroll
            for (int k = 0; k < 4; ++k) {
                unsigned long long S  = (Bc[k] >> lane) | ((Bn[k] << 1) << li);
                unsigned long long SL = (rbc[k] >> li)  | ((rbp[k] << 1) << lane);
                uint32_t ss = (uint32_t)S;
                uint32_t sl = (uint32_t)SL;
                a[k]  = 4 * __builtin_ctz(ss | SEN) + k;
                bb[k] = 4 * __builtin_ctz((ss >> 1) | SEN) + 4 + k;
                c[k]  = 4 * __builtin_ctz(sl | SEN) - k;
                e[k]  = 4 * __builtin_ctz((sl >> 1) | SEN) + 4 - k;
            }
            const int A3 = a[3], A2 = imin(a[2], A3), A1 = imin(a[1], A2), A0 = imin(a[0], A1);
            const int B0 = bb[0], B1 = imin(B0, bb[1]), B2 = imin(B1, bb[2]);
            const int C0 = c[0], C1 = imin(C0, c[1]), C2 = imin(C1, c[2]), C3 = imin(C2, c[3]);
            const int E3 = e[3], E2 = imin(e[2], E3), E1 = imin(e[1], E2);

            int d0 = imin(imin(A0,               imin(C0, E1)    ), MAXT);
            int d1 = imin(imin(imin(A1, B0) - 1, imin(C1, E2) + 1), MAXT);
            int d2 = imin(imin(imin(A2, B1) - 2, imin(C2, E3) + 2), MAXT);
            int d3 = imin(imin(imin(A3, B2) - 3, C3 + 3          ), MAXT);
            pk0 = (uint32_t)(d0 * d0) | ((uint32_t)(d1 * d1) << 16);
            pk1 = (uint32_t)(d2 * d2) | ((uint32_t)(d3 * d3) << 16);
        } else {
            pk0 = pk1 = BIGSQ | (BIGSQ << 16);   // outside image: never wins
        }
        *(uint2*)&s[lr & (RING - 1)][lane << 2] = make_uint2(pk0, pk1);
    };

    auto relax_row = [&](int j) {
        const int lc = j + 21;
        const int cg = lane << 2;    // 4 adjacent cols per lane, 64 lanes = full row
        uint2 q = *(const uint2*)&s[lc & (RING - 1)][cg];
        uint32_t v0 = q.x & 0xffff, v1 = q.x >> 16;
        uint32_t v2 = q.y & 0xffff, v3 = q.y >> 16;
        for (int d = 1; d <= MAXT; ++d) {
            const uint32_t dd = (uint32_t)(d * d);
            uint32_t h  = v0 > v1 ? v0 : v1;
            uint32_t h2 = v2 > v3 ? v2 : v3;
            h = h > h2 ? h : h2;
            if (__all(dd >= h)) break;   // further candidates >= d^2 >= current
            uint2 aa = *(const uint2*)&s[(lc - d) & (RING - 1)][cg];
            uint2 bq = *(const uint2*)&s[(lc + d) & (RING - 1)][cg];
            const uint32_t dd2 = dd * 0x10001u;   // packed u16 add (<=882, no carry)
            uint32_t A0 = aa.x + dd2, A1 = aa.y + dd2;
            uint32_t B0 = bq.x + dd2, B1 = bq.y + dd2;
            v0 = umin32(v0, umin32(A0 & 0xffff, B0 & 0xffff));
            v1 = umin32(v1, umin32(A0 >> 16,    B0 >> 16));
            v2 = umin32(v2, umin32(A1 & 0xffff, B1 & 0xffff));
            v3 = umin32(v3, umin32(A1 >> 16,    B1 >> 16));
        }
        floatx4 o;
        o.x = sqrtf((float)v0);
        o.y = sqrtf((float)v1);
        o.z = sqrtf((float)v2);
        o.w = sqrtf((float)v3);
        floatx4* op = (floatx4*)&out[base + (long long)(y0 + j) * WW + x0 + cg];
        __builtin_nontemporal_store(o, op);
    };

    // ---- prologue: ring rows 0..57 (relax of rows [0,16) reads lr in [0,57]) ----
    for (int lr = w; lr < 58; lr += 8) {
        HRow r = load_row(lr);
        compute_store(lr, r);
    }
    __syncthreads();

    // ---- main: 8 iters x 16 rows; h-pass writes slots disjoint from relax reads ----
    for (int i = 0; i < 8; ++i) {
        const int lr0 = 58 + (i << 4) + (w << 1);
        const int lr1 = lr0 + 1;
        const bool g0 = lr0 < WROWS, g1 = lr1 < WROWS;
        HRow R0, R1;
        if (g0) R0 = load_row(lr0);      // issue early: latency hides under relax
        if (g1) R1 = load_row(lr1);

        relax_row((i << 4) + w);
        relax_row((i << 4) + 8 + w);

        if (g0) compute_store(lr0, R0);
        if (g1) compute_store(lr1, R1);
        __syncthreads();
    }
}

extern "C" void kernel_launch(void* const* d_in, const int* in_sizes, int n_in,
                              void* d_out, int out_size, void* d_ws, size_t ws_size,
                              hipStream_t stream) {
    const int* unt = (const int*)d_in[0];
    float* out     = (float*)d_out;
    fused<<<dim3((WW / TW) * (HH / BH) * BB), 512, 0, stream>>>(unt, out);
}

// Round 10
// 37.980 us; speedup vs baseline: 1.4683x; 1.2158x over previous
//
#include <hip/hip_runtime.h>
#include <cstdint>

#define BB 4
#define HH 2048
#define WW 2048
#define MAXT 21
#define BIGSQ 441        // MAXT^2
#define SEN (1u << 6)    // sentinel bit: quad-dist t=6 -> d>=24 -> clamps to 21

typedef float floatx4 __attribute__((ext_vector_type(4)));
typedef unsigned short u16x2 __attribute__((ext_vector_type(2)));

static __device__ __forceinline__ uint32_t umax32(uint32_t a, uint32_t b) { return a > b ? a : b; }
static __device__ __forceinline__ int imin(int a, int b) { return a < b ? a : b; }

// ---------------- Pass A: horizontal capped nearest-obstacle distance ----------------
// One wave = one full row (2048 px), uint4 loads (16 B = 4 px per lane).
// Quad-phase ballot scheme (R7-validated): superchunk = 256 px; mask B_k bit l =
// obstacle at px 256j + 4l + k. Funnel-aligned masks, sentinel-capped ctz,
// per-subpixel combine via prefix/suffix mins. All indexing in int32.
__global__ __launch_bounds__(256) void hpass(const int* __restrict__ in,
                                             uint8_t* __restrict__ dh) {
    const int tid  = threadIdx.x;
    const int lane = tid & 63;
    const int w    = tid >> 6;
    const int row  = (blockIdx.x << 2) + w;   // 4 rows per block; rows never cross batches
    const int ro   = row * WW;                 // < 2^24, int32 safe
    const int* rp  = in + ro;
    const int li   = 63 - lane;

    uint4 q[8];
    #pragma unroll
    for (int j = 0; j < 8; ++j)
        q[j] = *(const uint4*)(rp + (j << 8) + (lane << 2));

    unsigned long long Bc[4], Bn[4], rbc[4], rbp[4];
    #pragma unroll
    for (int k = 0; k < 4; ++k) rbp[k] = 0;
    Bc[0] = __ballot(q[0].x != 0);
    Bc[1] = __ballot(q[0].y != 0);
    Bc[2] = __ballot(q[0].z != 0);
    Bc[3] = __ballot(q[0].w != 0);
    #pragma unroll
    for (int k = 0; k < 4; ++k) rbc[k] = __brevll(Bc[k]);

    #pragma unroll
    for (int j = 0; j < 8; ++j) {
        if (j < 7) {
            Bn[0] = __ballot(q[j + 1].x != 0);
            Bn[1] = __ballot(q[j + 1].y != 0);
            Bn[2] = __ballot(q[j + 1].z != 0);
            Bn[3] = __ballot(q[j + 1].w != 0);
        } else {
            Bn[0] = Bn[1] = Bn[2] = Bn[3] = 0;
        }

        int a[4], b[4], c[4], e[4];
        #pragma unroll
        for (int k = 0; k < 4; ++k) {
            unsigned long long S  = (Bc[k] >> lane) | ((Bn[k] << 1) << li);
            unsigned long long SL = (rbc[k] >> li)  | ((rbp[k] << 1) << lane);
            uint32_t s  = (uint32_t)S;
            uint32_t sl = (uint32_t)SL;
            a[k] = 4 * __builtin_ctz(s | SEN) + k;
            b[k] = 4 * __builtin_ctz((s >> 1) | SEN) + 4 + k;
            c[k] = 4 * __builtin_ctz(sl | SEN) - k;
            e[k] = 4 * __builtin_ctz((sl >> 1) | SEN) + 4 - k;
        }
        const int A3 = a[3], A2 = imin(a[2], A3), A1 = imin(a[1], A2), A0 = imin(a[0], A1);
        const int B0 = b[0], B1 = imin(B0, b[1]), B2 = imin(B1, b[2]);
        const int C0 = c[0], C1 = imin(C0, c[1]), C2 = imin(C1, c[2]), C3 = imin(C2, c[3]);
        const int E3 = e[3], E2 = imin(e[2], E3), E1 = imin(e[1], E2);

        int d0 = imin(imin(A0,               imin(C0, E1)    ), MAXT);
        int d1 = imin(imin(imin(A1, B0) - 1, imin(C1, E2) + 1), MAXT);
        int d2 = imin(imin(imin(A2, B1) - 2, imin(C2, E3) + 2), MAXT);
        int d3 = imin(imin(imin(A3, B2) - 3, C3 + 3          ), MAXT);

        uint32_t pk = (uint32_t)d0 | ((uint32_t)d1 << 8) | ((uint32_t)d2 << 16) | ((uint32_t)d3 << 24);
        *(uint32_t*)(dh + ro + (j << 8) + (lane << 2)) = pk;

        #pragma unroll
        for (int k = 0; k < 4; ++k) {
            rbp[k] = rbc[k];
            Bc[k]  = Bn[k];
            rbc[k] = __brevll(Bn[k]);
        }
    }
}

// ---------------- Pass B: vertical relax + sqrt ----------------
// 128x64 output tile, LDS dh^2 (u16) 106 rows. uint4 staging (16 px/lane),
// relax in packed-u16 SIMD (v_pk_min/add/max_u16: 2 px per instr,
// min(A,B)+dd folds the two adds), nontemporal float4 stores, XCD swizzle.
__global__ __launch_bounds__(256) void vpass(const uint8_t* __restrict__ dh,
                                             float* __restrict__ out) {
    __shared__ uint16_t s[106][128];   // 27136 B
    const int tid = threadIdx.x;
    const int bid = blockIdx.x;                   // 2048 blocks, 2048 % 8 == 0
    const int swz = (bid & 7) * 256 + (bid >> 3); // bijective XCD chunking
    const int x0  = (swz & 15) << 7;
    const int y0  = ((swz >> 4) & 31) << 6;
    const int b   = swz >> 9;
    const int base = b * (HH * WW);               // < 2^24, int32 safe

    // stage: 16 dh bytes per lane-iter -> 16 squared u16 -> two b128 LDS writes
    for (int i = tid; i < 106 * 8; i += 256) {
        const int r   = i >> 3;
        const int c16 = (i & 7) << 4;
        const int gy  = y0 - 21 + r;
        uint4 pk0, pk1;
        if (gy >= 0 && gy < HH) {
            const uint8_t* p = dh + base + gy * WW + x0 + c16;
            uint4 u = *(const uint4*)p;
            #pragma unroll
            for (int h = 0; h < 4; ++h) {
                uint32_t word = (&u.x)[h];
                uint32_t e0 = word & 0xff, e1 = (word >> 8) & 0xff;
                uint32_t e2 = (word >> 16) & 0xff, e3 = word >> 24;
                uint32_t lo = (e0 * e0) | ((e1 * e1) << 16);
                uint32_t hi = (e2 * e2) | ((e3 * e3) << 16);
                if (h < 2) { (&pk0.x)[h * 2] = lo; (&pk0.x)[h * 2 + 1] = hi; }
                else       { (&pk1.x)[(h - 2) * 2] = lo; (&pk1.x)[(h - 2) * 2 + 1] = hi; }
            }
        } else {
            pk0.x = pk0.y = pk0.z = pk0.w = BIGSQ | (BIGSQ << 16);
            pk1 = pk0;
        }
        *(uint4*)&s[r][c16]     = pk0;
        *(uint4*)&s[r][c16 + 8] = pk1;
    }
    __syncthreads();

    const int lane = tid & 63;
    const int w    = tid >> 6;
    const int cg   = (lane & 31) << 2;   // 4 adjacent cols per lane
    const int rofs = lane >> 5;          // row offset 0/1
    for (int k = 0; k < 8; ++k) {
        const int j  = (w << 4) + (k << 1) + rofs;
        const int yl = 21 + j;

        uint2 q = *(const uint2*)&s[yl][cg];
        u16x2 V0 = __builtin_bit_cast(u16x2, q.x);
        u16x2 V1 = __builtin_bit_cast(u16x2, q.y);

        for (int d = 1; d <= MAXT; ++d) {
            const uint32_t dd = (uint32_t)(d * d);
            u16x2 M = __builtin_elementwise_max(V0, V1);        // v_pk_max_u16
            uint32_t m32 = __builtin_bit_cast(uint32_t, M);
            uint32_t h = umax32(m32 & 0xffffu, m32 >> 16);
            if (__all(dd >= h)) break;   // further candidates >= d^2 >= current
            uint2 a  = *(const uint2*)&s[yl - d][cg];
            uint2 bq = *(const uint2*)&s[yl + d][cg];
            u16x2 D  = { (unsigned short)dd, (unsigned short)dd };
            u16x2 A0 = __builtin_bit_cast(u16x2, a.x),  A1 = __builtin_bit_cast(u16x2, a.y);
            u16x2 B0 = __builtin_bit_cast(u16x2, bq.x), B1 = __builtin_bit_cast(u16x2, bq.y);
            // min(A,B)+D == min(A+D, B+D); values <= 882, no u16 overflow
            V0 = __builtin_elementwise_min(V0, (u16x2)(__builtin_elementwise_min(A0, B0) + D));
            V1 = __builtin_elementwise_min(V1, (u16x2)(__builtin_elementwise_min(A1, B1) + D));
        }

        const uint32_t r0 = __builtin_bit_cast(uint32_t, V0);
        const uint32_t r1 = __builtin_bit_cast(uint32_t, V1);
        floatx4 o;
        o.x = sqrtf((float)(r0 & 0xffffu));
        o.y = sqrtf((float)(r0 >> 16));
        o.z = sqrtf((float)(r1 & 0xffffu));
        o.w = sqrtf((float)(r1 >> 16));
        floatx4* op = (floatx4*)&out[base + (y0 + j) * WW + x0 + cg];
        __builtin_nontemporal_store(o, op);
    }
}

extern "C" void kernel_launch(void* const* d_in, const int* in_sizes, int n_in,
                              void* d_out, int out_size, void* d_ws, size_t ws_size,
                              hipStream_t stream) {
    const int* unt = (const int*)d_in[0];
    uint8_t* dh    = (uint8_t*)d_ws;             // BB*HH*WW bytes = 16.7 MB scratch
    float* out     = (float*)d_out;

    hpass<<<dim3(BB * HH / 4), 256, 0, stream>>>(unt, dh);
    vpass<<<dim3(WW / 128 * HH / 64 * BB), 256, 0, stream>>>(dh, out);
}